// Round 8
// baseline (969.964 us; speedup 1.0000x reference)
//
#include <hip/hip_runtime.h>
#include <math.h>

#define NPTS 256
#define NSRC 1024
#define NITER 100
#define KCONV 577.0780163555854f         // log2(e)/eps
#define INV_KC 0.0017328679513998632f    // eps*ln2
#define EPS_LBC (-0.013862943611198906f) // eps*ln(1/256)
#define EPSQ 0.0025f
#define NEG_BIG (-1e30f)
#define TAGM 15u

#define EXP2F(x) __builtin_amdgcn_exp2f(x)
#define LOG2F(x) __builtin_amdgcn_logf(x)
#define F4E(v,e) ((e)==0?(v).x:(e)==1?(v).y:(e)==2?(v).z:(v).w)

// exchange: img i @ i*4096 words: parity p at +p*2048, block b's 256 partials at +b*256
#define WS_PART_W 32768

__device__ __forceinline__ void stp(unsigned int* p, float v, unsigned int tag) {
  __hip_atomic_store(p, (__float_as_uint(v) & ~TAGM) | tag,
                     __ATOMIC_RELAXED, __HIP_MEMORY_SCOPE_AGENT);
}
__device__ __forceinline__ unsigned int ldp(const unsigned int* p) {
  return __hip_atomic_load(p, __ATOMIC_RELAXED, __HIP_MEMORY_SCOPE_AGENT);
}

__global__ __launch_bounds__(1024)
void ot_sinkhorn(const float* __restrict__ dens_all,
                 const float* __restrict__ pts_all,
                 unsigned int* __restrict__ wsu)
{
  // ---- ab ----
  __shared__ __align__(16) float pxP[2][320], pyP[2][320];   // padded 16x20
  __shared__ __align__(16) float G_L[320];
  __shared__ __align__(16) float F_own[2][128];
  __shared__ __align__(16) float ela_own[2][128], a_own[2][128];
  // ---- bb ----
  __shared__ __align__(16) float pxL[NPTS], pyL[NPTS], FbS[NPTS], GbS[NPTS];
  // ---- aa ----
  __shared__ __align__(16) float FaL[NSRC], TaL[32 * 33], PM[16 * 33], CM[32];
  __shared__ float red[16];

  const int tid = threadIdx.x;
  const int bid = blockIdx.x;
  float* partials = (float*)(wsu + WS_PART_W);
  float acc = 0.0f;

  if (bid < 32) {
    // ============ ot_ab : 4 pairs x 8 blocks, ONE tagged partial-exchange/iter ============
    const int team = bid >> 3, sub = bid & 7;
    unsigned int* EX[2] = { wsu + (team * 2) * 4096, wsu + (team * 2 + 1) * 4096 };

    for (int s = 0; s < 2; ++s) {
      const int img = team * 2 + s;
      const float* dens = dens_all + img * NSRC;
      const float* pts = pts_all + img * (NPTS * 2);
      if (tid < NPTS) {
        pxP[s][(tid >> 4) * 20 + (tid & 15)] = pts[2 * tid];
        pyP[s][(tid >> 4) * 20 + (tid & 15)] = pts[2 * tid + 1];
      }
      if (tid < 128) {
        float a = dens[sub * 128 + tid];
        a_own[s][tid] = a;
        float ela = (a > 0.0f) ? EPSQ * __logf(a) : NEG_BIG;
        ela_own[s][tid] = ela;
        F_own[s][tid] = ela;                     // f = 0 (t-units)
      }
    }
    __syncthreads();

    const int jp = tid >> 2, sl = tid & 3;       // partial: 4 lanes per target
    const int cl = tid >> 3, ch = tid & 7;       // f-half: 8 lanes per cell
    const int cc = sub * 128 + cl;
    const float cx = (float)((cc & 31) * 8 + 4);
    const float cy = (float)((cc >> 5) * 8 + 4);

    float tt[32];

    // partial(j) = LSE over this block's 128 cells (4 rows of 32), store tagged
    auto partial_store = [&](int s, int k) {
      const float pxj = pxP[s][(jp >> 4) * 20 + (jp & 15)];
      const float pyj = pyP[s][(jp >> 4) * 20 + (jp & 15)];
      const float ry = (float)((sub * 4 + sl) * 8 + 4);
      const float dy = ry - pyj, dy2 = dy * dy;
      const float4* F4 = (const float4*)F_own[s];
      float m = -INFINITY;
      #pragma unroll
      for (int q = 0; q < 8; ++q) {
        float4 Fv = F4[sl * 8 + q];
        #pragma unroll
        for (int e = 0; e < 4; ++e) {
          float dx = (float)((q * 4 + e) * 8 + 4) - pxj;
          float v = fmaf(fmaf(dx, dx, dy2), -0.5f, F4E(Fv, e));
          tt[q * 4 + e] = v; m = fmaxf(m, v);
        }
      }
      m = fmaxf(m, __shfl_xor(m, 1, 64));
      m = fmaxf(m, __shfl_xor(m, 2, 64));
      const float mk = m * KCONV;
      float ss = 0.0f;
      #pragma unroll
      for (int i = 0; i < 32; ++i) ss += EXP2F(fmaf(tt[i], KCONV, -mk));
      ss += __shfl_xor(ss, 1, 64);
      ss += __shfl_xor(ss, 2, 64);
      if (sl == 0)
        stp(EX[s] + (k & 1) * 2048 + sub * 256 + jp,
            m + LOG2F(ss) * INV_KC, (unsigned)k & TAGM);
    };

    // poll all 8 blocks' partials for target tid, merge in registers -> g
    auto poll_merge = [&](int s, int k) -> float {
      float g = 0.0f;
      if (tid < 256) {
        const unsigned int* base = EX[s] + (k & 1) * 2048 + tid;
        const unsigned tg = (unsigned)k & TAGM;
        unsigned u[8];
        for (;;) {
          unsigned bad = 0;
          #pragma unroll
          for (int b = 0; b < 8; ++b) { u[b] = ldp(base + b * 256); bad |= (u[b] & TAGM) ^ tg; }
          if (__all(bad == 0)) break;
          __builtin_amdgcn_s_sleep(1);
        }
        float vv[8]; float m = -INFINITY;
        #pragma unroll
        for (int b = 0; b < 8; ++b) { vv[b] = __uint_as_float(u[b] & ~TAGM); m = fmaxf(m, vv[b]); }
        const float mk = m * KCONV;
        float ss = 0.0f;
        #pragma unroll
        for (int b = 0; b < 8; ++b) ss += EXP2F(fmaf(vv[b], KCONV, -mk));
        g = -(m + LOG2F(ss) * INV_KC);
        G_L[(tid >> 4) * 20 + (tid & 15)] = g + EPS_LBC;
      }
      __syncthreads();
      return g;
    };

    auto fhalf = [&](int s, int k) {
      const float4* GL4 = (const float4*)G_L;
      const float4* px4 = (const float4*)pxP[s];
      const float4* py4 = (const float4*)pyP[s];
      float m = -INFINITY;
      #pragma unroll
      for (int q = 0; q < 8; ++q) {
        int gi = 2 * ch + (q >> 2);
        float4 pxv = px4[gi * 5 + (q & 3)], pyv = py4[gi * 5 + (q & 3)], Gv = GL4[gi * 5 + (q & 3)];
        #pragma unroll
        for (int e = 0; e < 4; ++e) {
          float dx = F4E(pxv, e) - cx, dq = F4E(pyv, e) - cy;
          float v = fmaf(fmaf(dq, dq, dx * dx), -0.5f, F4E(Gv, e));
          tt[q * 4 + e] = v; m = fmaxf(m, v);
        }
      }
      m = fmaxf(m, __shfl_xor(m, 1, 64));
      m = fmaxf(m, __shfl_xor(m, 2, 64));
      m = fmaxf(m, __shfl_xor(m, 4, 64));
      const float mk = m * KCONV;
      float ss = 0.0f;
      #pragma unroll
      for (int i = 0; i < 32; ++i) ss += EXP2F(fmaf(tt[i], KCONV, -mk));
      ss += __shfl_xor(ss, 1, 64);
      ss += __shfl_xor(ss, 2, 64);
      ss += __shfl_xor(ss, 4, 64);
      if (ch == 0) {
        float f = -(m + LOG2F(ss) * INV_KC);
        F_own[s][cl] = f + ela_own[s][cl];
        if (k == NITER) acc += a_own[s][cl] * f;   // sum a*f^100
      }
    };

    partial_store(0, 1);
    partial_store(1, 1);
    for (int k = 1; k <= NITER; ++k) {
      poll_merge(0, k);
      fhalf(0, k);
      __syncthreads();
      partial_store(0, k + 1);     // A's hop hides under B's whole phase
      poll_merge(1, k);
      fhalf(1, k);
      __syncthreads();
      partial_store(1, k + 1);
    }
    {
      float gA = poll_merge(0, NITER + 1);         // g^101 = U(f^100)
      if (sub == 0 && tid < 256) acc += gA * (1.0f / 256.0f);
      float gB = poll_merge(1, NITER + 1);
      if (sub == 0 && tid < 256) acc += gB * (1.0f / 256.0f);
    }
  } else if (bid < 40) {
    // ============ ot_bb : one block, in-LDS ============
    const int img = bid - 32;
    const float* pts = pts_all + img * (NPTS * 2);
    if (tid < NPTS) {
      pxL[tid] = pts[2 * tid];
      pyL[tid] = pts[2 * tid + 1];
      FbS[tid] = EPS_LBC;                          // f = 0
    }
    __syncthreads();

    const int cl = tid >> 4, ch = tid & 15;
    float4 px4[4], py4[4];
    #pragma unroll
    for (int k = 0; k < 4; ++k) {
      px4[k] = *(const float4*)(pxL + ch * 16 + k * 4);
      py4[k] = *(const float4*)(pyL + ch * 16 + k * 4);
    }
    const float4* Fb4 = (const float4*)FbS;
    const float4* Gb4 = (const float4*)GbS;

    float tt[16];
    for (int it = 0;; ++it) {
      float4 A4[4];
      #pragma unroll
      for (int k = 0; k < 4; ++k) A4[k] = Fb4[ch * 4 + k];
      #pragma unroll 1
      for (int p = 0; p < 4; ++p) {
        const int tj = p * 64 + cl;
        const float qx = pxL[tj], qy = pyL[tj];
        float m = -INFINITY;
        #pragma unroll
        for (int k = 0; k < 4; ++k) {
          #pragma unroll
          for (int e = 0; e < 4; ++e) {
            float dx = F4E(px4[k], e) - qx;
            float dyq = F4E(py4[k], e) - qy;
            float u = fmaf(dyq, dyq, dx * dx);
            float v = fmaf(u, -0.5f, F4E(A4[k], e));
            tt[k * 4 + e] = v; m = fmaxf(m, v);
          }
        }
        #pragma unroll
        for (int o = 1; o < 16; o <<= 1) m = fmaxf(m, __shfl_xor(m, o, 64));
        const float mk = m * KCONV;
        float s = 0.0f;
        #pragma unroll
        for (int i = 0; i < 16; ++i) s += EXP2F(fmaf(tt[i], KCONV, -mk));
        #pragma unroll
        for (int o = 1; o < 16; o <<= 1) s += __shfl_xor(s, o, 64);
        const float g = -(m + LOG2F(s) * INV_KC);
        if (it == NITER) { if (ch == 0) acc += g * (1.0f / 256.0f); }
        else if (ch == 0) GbS[tj] = g + EPS_LBC;
      }
      if (it == NITER) break;
      __syncthreads();

      float4 B4[4];
      #pragma unroll
      for (int k = 0; k < 4; ++k) B4[k] = Gb4[ch * 4 + k];
      #pragma unroll 1
      for (int p = 0; p < 4; ++p) {
        const int tj = p * 64 + cl;
        const float qx = pxL[tj], qy = pyL[tj];
        float m = -INFINITY;
        #pragma unroll
        for (int k = 0; k < 4; ++k) {
          #pragma unroll
          for (int e = 0; e < 4; ++e) {
            float dx = F4E(px4[k], e) - qx;
            float dyq = F4E(py4[k], e) - qy;
            float u = fmaf(dyq, dyq, dx * dx);
            float v = fmaf(u, -0.5f, F4E(B4[k], e));
            tt[k * 4 + e] = v; m = fmaxf(m, v);
          }
        }
        #pragma unroll
        for (int o = 1; o < 16; o <<= 1) m = fmaxf(m, __shfl_xor(m, o, 64));
        const float mk = m * KCONV;
        float s = 0.0f;
        #pragma unroll
        for (int i = 0; i < 16; ++i) s += EXP2F(fmaf(tt[i], KCONV, -mk));
        #pragma unroll
        for (int o = 1; o < 16; o <<= 1) s += __shfl_xor(s, o, 64);
        if (ch == 0) {
          const float f = -(m + LOG2F(s) * INV_KC);
          FbS[tj] = f + EPS_LBC;
          if (it == NITER - 1) acc += f * (1.0f / 256.0f);
        }
      }
      __syncthreads();
    }
  } else {
    // ============ ot_aa : one block, separable LSE + verified diagonal collapse ============
    const int img = bid - 40;
    const float* dens = dens_all + img * NSRC;
    const float d_np = dens[tid];
    const float a_np = d_np;
    const float epsla_np = (d_np > 0.0f) ? EPSQ * __logf(d_np) : NEG_BIG;
    float myF = epsla_np;
    FaL[tid] = myF;
    __syncthreads();

    const int w = tid >> 6, lane = tid & 63;
    const int q1 = tid & 31, r1 = tid >> 5;
    const int q2 = q1, r2 = r1;

    auto aa_half = [&]() -> float {
      float cp = fmaxf(myF, __shfl_xor(myF, 32, 64));
      if (lane < 32) PM[w * 33 + lane] = cp;
      __syncthreads();
      if (tid < 32) {
        float cm = -INFINITY;
        #pragma unroll
        for (int w2 = 0; w2 < 16; ++w2) cm = fmaxf(cm, PM[w2 * 33 + tid]);
        CM[tid] = cm;
      }
      __syncthreads();
      const float fmx = CM[q1];
      float Tv;
      if (__all(fmx - 32.0f <= myF - 0.25f)) {
        Tv = myF;
      } else {
        float tv[32]; float m = -INFINITY; float d = (float)(-r1);
        #pragma unroll
        for (int rr = 0; rr < 32; ++rr) {
          float v = fmaf(d * d, -32.0f, FaL[rr * 32 + q1]);
          tv[rr] = v; m = fmaxf(m, v); d += 1.0f;
        }
        const float mk = m * KCONV; float s = 0.0f;
        #pragma unroll
        for (int rr = 0; rr < 32; ++rr) s += EXP2F(fmaf(tv[rr], KCONV, -mk));
        Tv = m + LOG2F(s) * INV_KC;
      }
      TaL[q1 * 33 + r1] = Tv;
      __syncthreads();
      float tmx = Tv;
      #pragma unroll
      for (int o = 1; o < 32; o <<= 1) tmx = fmaxf(tmx, __shfl_xor(tmx, o, 64));
      float outv;
      if (__all(tmx - 32.0f <= Tv - 0.25f)) {
        outv = Tv;
      } else {
        float tv[32]; float m = -INFINITY; float d = (float)(-q2);
        #pragma unroll
        for (int qi = 0; qi < 32; ++qi) {
          float v = fmaf(d * d, -32.0f, TaL[qi * 33 + r2]);
          tv[qi] = v; m = fmaxf(m, v); d += 1.0f;
        }
        const float mk = m * KCONV; float s = 0.0f;
        #pragma unroll
        for (int qi = 0; qi < 32; ++qi) s += EXP2F(fmaf(tv[qi], KCONV, -mk));
        outv = m + LOG2F(s) * INV_KC;
      }
      __syncthreads();
      return -outv;
    };

    for (int it = 0;; ++it) {
      float gpot = aa_half();
      if (it == NITER) { acc += a_np * gpot; break; }
      myF = gpot + epsla_np; FaL[tid] = myF;
      __syncthreads();
      float fpot = aa_half();
      if (it == NITER - 1) acc += a_np * fpot;
      myF = fpot + epsla_np; FaL[tid] = myF;
      __syncthreads();
    }
  }

  // ---- block reduction + per-block partial ----
  {
    #pragma unroll
    for (int o = 32; o; o >>= 1) acc += __shfl_xor(acc, o, 64);
    __syncthreads();
    if ((tid & 63) == 0) red[tid >> 6] = acc;
    __syncthreads();
    if (tid == 0) {
      float tsum = 0.0f;
      #pragma unroll
      for (int k = 0; k < 16; ++k) tsum += red[k];
      partials[bid] = tsum;
    }
  }
}

__global__ void ot_finalize(const float* __restrict__ partials, float* __restrict__ out) {
  const int tid = threadIdx.x;
  float v = 0.0f;
  if (tid < 48) v = ((tid < 32) ? 1.0f : -0.5f) * partials[tid];
  #pragma unroll
  for (int o = 32; o; o >>= 1) v += __shfl_xor(v, o, 64);
  if (tid == 0) out[0] = v;
}

extern "C" void kernel_launch(void* const* d_in, const int* in_sizes, int n_in,
                              void* d_out, int out_size, void* d_ws, size_t ws_size,
                              hipStream_t stream) {
  const float* dens = (const float*)d_in[0];   // (8,1,32,32) f32
  const float* pts  = (const float*)d_in[1];   // (8,256,2)   f32
  unsigned int* wsu = (unsigned int*)d_ws;
  ot_sinkhorn<<<dim3(48), dim3(1024), 0, stream>>>(dens, pts, wsu);
  ot_finalize<<<dim3(1), dim3(64), 0, stream>>>((const float*)(wsu + WS_PART_W), (float*)d_out);
}

// Round 9
// 945.882 us; speedup vs baseline: 1.0255x; 1.0255x over previous
//
#include <hip/hip_runtime.h>
#include <math.h>

#define NPTS 256
#define NSRC 1024
#define NITER 100
#define KCONV 577.0780163555854f         // log2(e)/eps
#define INV_KC 0.0017328679513998632f    // eps*ln2
#define EPS_LBC (-0.013862943611198906f) // eps*ln(1/256)
#define EPSQ 0.0025f
#define NEG_BIG (-1e30f)
#define TAGM 15u

#define EXP2F(x) __builtin_amdgcn_exp2f(x)
#define LOG2F(x) __builtin_amdgcn_logf(x)
#define F4E(v,e) ((e)==0?(v).x:(e)==1?(v).y:(e)==2?(v).z:(v).w)

// exchange: img i @ i*16384 words; parity p at +p*8192; block b's 256 partials at +b*256
#define WS_PART_W 131072

__device__ __forceinline__ void stp(unsigned int* p, float v, unsigned int tag) {
  __hip_atomic_store(p, (__float_as_uint(v) & ~TAGM) | tag,
                     __ATOMIC_RELAXED, __HIP_MEMORY_SCOPE_AGENT);
}
__device__ __forceinline__ unsigned int ldp(const unsigned int* p) {
  return __hip_atomic_load(p, __ATOMIC_RELAXED, __HIP_MEMORY_SCOPE_AGENT);
}

__global__ __launch_bounds__(1024)
void ot_sinkhorn(const float* __restrict__ dens_all,
                 const float* __restrict__ pts_all,
                 unsigned int* __restrict__ wsu)
{
  // ---- ab ----
  __shared__ __align__(16) float pxP[2][320], pyP[2][320];   // padded 16x20
  __shared__ __align__(16) float G_L[320];
  __shared__ __align__(16) float F_own[2][32];
  __shared__ __align__(16) float a_own[2][32], ela_own[2][32];
  // ---- bb ----
  __shared__ __align__(16) float pxL[NPTS], pyL[NPTS], FbS[NPTS], GbS[NPTS];
  // ---- aa ----
  __shared__ __align__(16) float FaL[NSRC], TaL[32 * 33], PM[16 * 33], CM[32];
  __shared__ float red[16];

  const int tid = threadIdx.x;
  const int bid = blockIdx.x;
  float* partials = (float*)(wsu + WS_PART_W);
  float acc = 0.0f;

  if (bid < 128) {
    // ============ ot_ab : 4 teams x 32 blocks x 2 images, 1 tagged exchange/iter ============
    const int team = bid >> 5, sub = bid & 31;      // block owns grid row `sub` (32 cells)
    unsigned int* EX[2] = { wsu + (team * 2) * 16384, wsu + (team * 2 + 1) * 16384 };

    for (int s = 0; s < 2; ++s) {
      const int img = team * 2 + s;
      const float* dens = dens_all + img * NSRC;
      const float* pts = pts_all + img * (NPTS * 2);
      if (tid < NPTS) {
        pxP[s][(tid >> 4) * 20 + (tid & 15)] = pts[2 * tid];
        pyP[s][(tid >> 4) * 20 + (tid & 15)] = pts[2 * tid + 1];
      }
      if (tid < 32) {
        float a = dens[sub * 32 + tid];
        a_own[s][tid] = a;
        float ela = (a > 0.0f) ? EPSQ * __logf(a) : NEG_BIG;
        ela_own[s][tid] = ela;
        F_own[s][tid] = ela;                        // f = 0 (t-units)
      }
    }
    __syncthreads();

    const int jp = tid >> 2, sl = tid & 3;          // partial/merge: 4 lanes per target
    const int cl = tid >> 5, ch = tid & 31;         // fhalf: 32 lanes per cell
    const float cyb = (float)(sub * 8 + 4);         // block's row y
    const float cxf = (float)(cl * 8 + 4);          // fhalf cell x

    float tt[8];

    // per-target partial LSE over this block's 32 cells (one row), store tagged
    auto partial_store = [&](int s, int k) {
      const float pxj = pxP[s][(jp >> 4) * 20 + (jp & 15)];
      const float pyj = pyP[s][(jp >> 4) * 20 + (jp & 15)];
      const float dy = cyb - pyj;
      const float base = -0.5f * dy * dy;
      const float4* F4 = (const float4*)F_own[s];
      float m = -INFINITY;
      #pragma unroll
      for (int q4 = 0; q4 < 2; ++q4) {
        float4 Fv = F4[sl * 2 + q4];
        #pragma unroll
        for (int e = 0; e < 4; ++e) {
          float dx = (float)((sl * 8 + q4 * 4 + e) * 8 + 4) - pxj;
          float v = fmaf(dx * dx, -0.5f, base + F4E(Fv, e));
          tt[q4 * 4 + e] = v; m = fmaxf(m, v);
        }
      }
      m = fmaxf(m, __shfl_xor(m, 1, 64));
      m = fmaxf(m, __shfl_xor(m, 2, 64));
      const float mk = m * KCONV;
      float ss = 0.0f;
      #pragma unroll
      for (int i = 0; i < 8; ++i) ss += EXP2F(fmaf(tt[i], KCONV, -mk));
      ss += __shfl_xor(ss, 1, 64);
      ss += __shfl_xor(ss, 2, 64);
      if (sl == 0)
        stp(EX[s] + (k & 1) * 8192 + sub * 256 + jp,
            m + LOG2F(ss) * INV_KC, (unsigned)k & TAGM);
    };

    // poll 32 blocks' partials for target jp (8 per lane), lse-merge -> g, stage G_L
    auto merge = [&](int s, int k) -> float {
      const unsigned tg = (unsigned)k & TAGM;
      const unsigned int* base = EX[s] + (k & 1) * 8192 + jp;
      unsigned u[8];
      for (;;) {
        unsigned bad = 0;
        #pragma unroll
        for (int i = 0; i < 8; ++i) { u[i] = ldp(base + (sl * 8 + i) * 256); bad |= (u[i] & TAGM) ^ tg; }
        if (__all(bad == 0)) break;
        __builtin_amdgcn_s_sleep(1);
      }
      float vv[8]; float m = -INFINITY;
      #pragma unroll
      for (int i = 0; i < 8; ++i) { vv[i] = __uint_as_float(u[i] & ~TAGM); m = fmaxf(m, vv[i]); }
      const float mk = m * KCONV;
      float ss = 0.0f;
      #pragma unroll
      for (int i = 0; i < 8; ++i) ss += EXP2F(fmaf(vv[i], KCONV, -mk));
      #pragma unroll
      for (int o = 1; o < 4; o <<= 1) {
        float mo = __shfl_xor(m, o, 64), so = __shfl_xor(ss, o, 64);
        float mn = fmaxf(m, mo);
        ss = ss * EXP2F((m - mn) * KCONV) + so * EXP2F((mo - mn) * KCONV);
        m = mn;
      }
      float g = -(m + LOG2F(ss) * INV_KC);
      if (sl == 0) G_L[(jp >> 4) * 20 + (jp & 15)] = g + EPS_LBC;
      return g;
    };

    // f-update for this block's 32 cells over all 256 targets (32 lanes/cell)
    auto fhalf = [&](int s, int k) {
      const float4* px4 = (const float4*)pxP[s];
      const float4* py4 = (const float4*)pyP[s];
      const float4* GL4 = (const float4*)G_L;
      const int g0 = (ch >> 1) * 5 + (ch & 1) * 2;
      float m = -INFINITY;
      #pragma unroll
      for (int h2 = 0; h2 < 2; ++h2) {
        float4 pxv = px4[g0 + h2], pyv = py4[g0 + h2], Gv = GL4[g0 + h2];
        #pragma unroll
        for (int e = 0; e < 4; ++e) {
          float dx = F4E(pxv, e) - cxf, dq = F4E(pyv, e) - cyb;
          float v = fmaf(fmaf(dq, dq, dx * dx), -0.5f, F4E(Gv, e));
          tt[h2 * 4 + e] = v; m = fmaxf(m, v);
        }
      }
      #pragma unroll
      for (int o = 1; o < 32; o <<= 1) m = fmaxf(m, __shfl_xor(m, o, 64));
      const float mk = m * KCONV;
      float ss = 0.0f;
      #pragma unroll
      for (int i = 0; i < 8; ++i) ss += EXP2F(fmaf(tt[i], KCONV, -mk));
      #pragma unroll
      for (int o = 1; o < 32; o <<= 1) ss += __shfl_xor(ss, o, 64);
      if (ch == 0) {
        float f = -(m + LOG2F(ss) * INV_KC);
        F_own[s][cl] = f + ela_own[s][cl];
        if (k == NITER) acc += a_own[s][cl] * f;    // sum a*f^100
      }
    };

    partial_store(0, 1);
    partial_store(1, 1);
    for (int k = 1; k <= NITER; ++k) {
      merge(0, k);
      __syncthreads();
      fhalf(0, k);
      __syncthreads();
      partial_store(0, k + 1);    // A's hop hides under B's whole phase
      merge(1, k);
      __syncthreads();
      fhalf(1, k);
      __syncthreads();
      partial_store(1, k + 1);
    }
    if (sub == 0) {               // g^101 term, one block per team-image
      float gA = merge(0, NITER + 1);
      if (sl == 0) acc += gA * (1.0f / 256.0f);
      float gB = merge(1, NITER + 1);
      if (sl == 0) acc += gB * (1.0f / 256.0f);
    }
  } else if (bid < 136) {
    // ============ ot_bb : one block, in-LDS ============
    const int img = bid - 128;
    const float* pts = pts_all + img * (NPTS * 2);
    if (tid < NPTS) {
      pxL[tid] = pts[2 * tid];
      pyL[tid] = pts[2 * tid + 1];
      FbS[tid] = EPS_LBC;                           // f = 0
    }
    __syncthreads();

    const int cl = tid >> 4, ch = tid & 15;
    float4 px4[4], py4[4];
    #pragma unroll
    for (int k = 0; k < 4; ++k) {
      px4[k] = *(const float4*)(pxL + ch * 16 + k * 4);
      py4[k] = *(const float4*)(pyL + ch * 16 + k * 4);
    }
    const float4* Fb4 = (const float4*)FbS;
    const float4* Gb4 = (const float4*)GbS;

    float tt[16];
    for (int it = 0;; ++it) {
      float4 A4[4];
      #pragma unroll
      for (int k = 0; k < 4; ++k) A4[k] = Fb4[ch * 4 + k];
      #pragma unroll 1
      for (int p = 0; p < 4; ++p) {
        const int tj = p * 64 + cl;
        const float qx = pxL[tj], qy = pyL[tj];
        float m = -INFINITY;
        #pragma unroll
        for (int k = 0; k < 4; ++k) {
          #pragma unroll
          for (int e = 0; e < 4; ++e) {
            float dx = F4E(px4[k], e) - qx;
            float dyq = F4E(py4[k], e) - qy;
            float u = fmaf(dyq, dyq, dx * dx);
            float v = fmaf(u, -0.5f, F4E(A4[k], e));
            tt[k * 4 + e] = v; m = fmaxf(m, v);
          }
        }
        #pragma unroll
        for (int o = 1; o < 16; o <<= 1) m = fmaxf(m, __shfl_xor(m, o, 64));
        const float mk = m * KCONV;
        float s = 0.0f;
        #pragma unroll
        for (int i = 0; i < 16; ++i) s += EXP2F(fmaf(tt[i], KCONV, -mk));
        #pragma unroll
        for (int o = 1; o < 16; o <<= 1) s += __shfl_xor(s, o, 64);
        const float g = -(m + LOG2F(s) * INV_KC);
        if (it == NITER) { if (ch == 0) acc += g * (1.0f / 256.0f); }
        else if (ch == 0) GbS[tj] = g + EPS_LBC;
      }
      if (it == NITER) break;
      __syncthreads();

      float4 B4[4];
      #pragma unroll
      for (int k = 0; k < 4; ++k) B4[k] = Gb4[ch * 4 + k];
      #pragma unroll 1
      for (int p = 0; p < 4; ++p) {
        const int tj = p * 64 + cl;
        const float qx = pxL[tj], qy = pyL[tj];
        float m = -INFINITY;
        #pragma unroll
        for (int k = 0; k < 4; ++k) {
          #pragma unroll
          for (int e = 0; e < 4; ++e) {
            float dx = F4E(px4[k], e) - qx;
            float dyq = F4E(py4[k], e) - qy;
            float u = fmaf(dyq, dyq, dx * dx);
            float v = fmaf(u, -0.5f, F4E(B4[k], e));
            tt[k * 4 + e] = v; m = fmaxf(m, v);
          }
        }
        #pragma unroll
        for (int o = 1; o < 16; o <<= 1) m = fmaxf(m, __shfl_xor(m, o, 64));
        const float mk = m * KCONV;
        float s = 0.0f;
        #pragma unroll
        for (int i = 0; i < 16; ++i) s += EXP2F(fmaf(tt[i], KCONV, -mk));
        #pragma unroll
        for (int o = 1; o < 16; o <<= 1) s += __shfl_xor(s, o, 64);
        if (ch == 0) {
          const float f = -(m + LOG2F(s) * INV_KC);
          FbS[tj] = f + EPS_LBC;
          if (it == NITER - 1) acc += f * (1.0f / 256.0f);
        }
      }
      __syncthreads();
    }
  } else {
    // ============ ot_aa : one block, separable LSE + verified diagonal collapse ============
    const int img = bid - 136;
    const float* dens = dens_all + img * NSRC;
    const float d_np = dens[tid];
    const float a_np = d_np;
    const float epsla_np = (d_np > 0.0f) ? EPSQ * __logf(d_np) : NEG_BIG;
    float myF = epsla_np;
    FaL[tid] = myF;
    __syncthreads();

    const int w = tid >> 6, lane = tid & 63;
    const int q1 = tid & 31, r1 = tid >> 5;
    const int q2 = q1, r2 = r1;

    auto aa_half = [&]() -> float {
      float cp = fmaxf(myF, __shfl_xor(myF, 32, 64));
      if (lane < 32) PM[w * 33 + lane] = cp;
      __syncthreads();
      if (tid < 32) {
        float cm = -INFINITY;
        #pragma unroll
        for (int w2 = 0; w2 < 16; ++w2) cm = fmaxf(cm, PM[w2 * 33 + tid]);
        CM[tid] = cm;
      }
      __syncthreads();
      const float fmx = CM[q1];
      float Tv;
      if (__all(fmx - 32.0f <= myF - 0.25f)) {
        Tv = myF;
      } else {
        float tv[32]; float m = -INFINITY; float d = (float)(-r1);
        #pragma unroll
        for (int rr = 0; rr < 32; ++rr) {
          float v = fmaf(d * d, -32.0f, FaL[rr * 32 + q1]);
          tv[rr] = v; m = fmaxf(m, v); d += 1.0f;
        }
        const float mk = m * KCONV; float s = 0.0f;
        #pragma unroll
        for (int rr = 0; rr < 32; ++rr) s += EXP2F(fmaf(tv[rr], KCONV, -mk));
        Tv = m + LOG2F(s) * INV_KC;
      }
      TaL[q1 * 33 + r1] = Tv;
      __syncthreads();
      float tmx = Tv;
      #pragma unroll
      for (int o = 1; o < 32; o <<= 1) tmx = fmaxf(tmx, __shfl_xor(tmx, o, 64));
      float outv;
      if (__all(tmx - 32.0f <= Tv - 0.25f)) {
        outv = Tv;
      } else {
        float tv[32]; float m = -INFINITY; float d = (float)(-q2);
        #pragma unroll
        for (int qi = 0; qi < 32; ++qi) {
          float v = fmaf(d * d, -32.0f, TaL[qi * 33 + r2]);
          tv[qi] = v; m = fmaxf(m, v); d += 1.0f;
        }
        const float mk = m * KCONV; float s = 0.0f;
        #pragma unroll
        for (int qi = 0; qi < 32; ++qi) s += EXP2F(fmaf(tv[qi], KCONV, -mk));
        outv = m + LOG2F(s) * INV_KC;
      }
      __syncthreads();
      return -outv;
    };

    for (int it = 0;; ++it) {
      float gpot = aa_half();
      if (it == NITER) { acc += a_np * gpot; break; }
      myF = gpot + epsla_np; FaL[tid] = myF;
      __syncthreads();
      float fpot = aa_half();
      if (it == NITER - 1) acc += a_np * fpot;
      myF = fpot + epsla_np; FaL[tid] = myF;
      __syncthreads();
    }
  }

  // ---- block reduction + per-block partial ----
  {
    #pragma unroll
    for (int o = 32; o; o >>= 1) acc += __shfl_xor(acc, o, 64);
    __syncthreads();
    if ((tid & 63) == 0) red[tid >> 6] = acc;
    __syncthreads();
    if (tid == 0) {
      float tsum = 0.0f;
      #pragma unroll
      for (int k = 0; k < 16; ++k) tsum += red[k];
      partials[bid] = tsum;
    }
  }
}

__global__ void ot_finalize(const float* __restrict__ partials, float* __restrict__ out) {
  __shared__ float red2[3];
  const int tid = threadIdx.x;
  float v = 0.0f;
  if (tid < 144) v = ((tid < 128) ? 1.0f : -0.5f) * partials[tid];
  #pragma unroll
  for (int o = 32; o; o >>= 1) v += __shfl_xor(v, o, 64);
  if ((tid & 63) == 0) red2[tid >> 6] = v;
  __syncthreads();
  if (tid == 0) out[0] = red2[0] + red2[1] + red2[2];
}

extern "C" void kernel_launch(void* const* d_in, const int* in_sizes, int n_in,
                              void* d_out, int out_size, void* d_ws, size_t ws_size,
                              hipStream_t stream) {
  const float* dens = (const float*)d_in[0];   // (8,1,32,32) f32
  const float* pts  = (const float*)d_in[1];   // (8,256,2)   f32
  unsigned int* wsu = (unsigned int*)d_ws;
  ot_sinkhorn<<<dim3(144), dim3(1024), 0, stream>>>(dens, pts, wsu);
  ot_finalize<<<dim3(1), dim3(192), 0, stream>>>((const float*)(wsu + WS_PART_W), (float*)d_out);
}